// Round 1
// baseline (1758.381 us; speedup 1.0000x reference)
//
#include <hip/hip_runtime.h>
#include <math.h>

#define HDIM   7168
#define NEXP   256
#define NTOK   16384
#define TM     64
#define TK     32
#define KTILES (HDIM / TK)   // 224

// ---------------------------------------------------------------------------
// Phase 1: scores_for_choice[t][e] = sigmoid( X[t,:] . W[:,e] ) + bias[e]
// fp32 vector-ALU GEMM (no fp32 MFMA on CDNA4).
// Tile 64M x 256N x 32K, 256 threads, 8x8 per-thread micro-tile.
// 2-level accumulation (per-K-tile partial -> main) to keep logit error ~1e-6
// so top-k index decisions match the numpy reference.
// ---------------------------------------------------------------------------
__global__ __launch_bounds__(256, 1) void gemm_scores(
    const float* __restrict__ A,      // [NTOK][HDIM]
    const float* __restrict__ W,      // [HDIM][NEXP]
    const float* __restrict__ bias,   // [NEXP]
    float* __restrict__ scores)       // [NTOK][NEXP]
{
  __shared__ float a_s[TK][TM + 4];   // [32][68] k-major (A transposed); stride 68 keeps 16B align
  __shared__ float b_s[TK][NEXP];     // [32][256]

  const int tid  = threadIdx.x;
  const int m0   = blockIdx.x * TM;
  const int rowg = tid >> 5;          // 0..7  -> rows 8*rowg..+7
  const int colg = tid & 31;          // 0..31 -> cols 8*colg..+7

  // staging coordinates
  const int am = tid >> 3;            // 0..31 (and +32 for second float4)
  const int ak = (tid & 7) << 2;      // 0..28 step 4
  const int bk = tid >> 6;            // 0..3 (k-row, stride 4)
  const int bn = (tid & 63) << 2;     // 0..252 step 4

  const float* Ap = A + (size_t)(m0 + am) * HDIM + ak;
  const float* Wp = W + (size_t)bk * NEXP + bn;

  float4 pa0, pa1, pb[8];
  pa0 = *(const float4*)(Ap);
  pa1 = *(const float4*)(Ap + (size_t)32 * HDIM);
#pragma unroll
  for (int i = 0; i < 8; ++i)
    pb[i] = *(const float4*)(Wp + (size_t)(4 * i) * NEXP);

  float accm[8][8];
#pragma unroll
  for (int mi = 0; mi < 8; ++mi)
#pragma unroll
    for (int ni = 0; ni < 8; ++ni) accm[mi][ni] = 0.f;

  for (int kt = 0; kt < KTILES; ++kt) {
    __syncthreads();
    // commit staged tile to LDS (A transposed, scalar scatter; B as float4)
    a_s[ak + 0][am]      = pa0.x;
    a_s[ak + 1][am]      = pa0.y;
    a_s[ak + 2][am]      = pa0.z;
    a_s[ak + 3][am]      = pa0.w;
    a_s[ak + 0][am + 32] = pa1.x;
    a_s[ak + 1][am + 32] = pa1.y;
    a_s[ak + 2][am + 32] = pa1.z;
    a_s[ak + 3][am + 32] = pa1.w;
#pragma unroll
    for (int i = 0; i < 8; ++i)
      *(float4*)(&b_s[bk + 4 * i][bn]) = pb[i];
    __syncthreads();

    // prefetch next K-tile into registers (hidden under the 2048-FMA compute)
    if (kt + 1 < KTILES) {
      const float* Ap2 = Ap + (size_t)(kt + 1) * TK;
      pa0 = *(const float4*)(Ap2);
      pa1 = *(const float4*)(Ap2 + (size_t)32 * HDIM);
      const float* Wp2 = Wp + (size_t)(kt + 1) * TK * NEXP;
#pragma unroll
      for (int i = 0; i < 8; ++i)
        pb[i] = *(const float4*)(Wp2 + (size_t)(4 * i) * NEXP);
    }

    float acct[8][8];
#pragma unroll
    for (int mi = 0; mi < 8; ++mi)
#pragma unroll
      for (int ni = 0; ni < 8; ++ni) acct[mi][ni] = 0.f;

#pragma unroll 8
    for (int k = 0; k < TK; ++k) {
      float4 a0 = *(const float4*)(&a_s[k][(rowg << 3) + 0]);
      float4 a1 = *(const float4*)(&a_s[k][(rowg << 3) + 4]);
      float4 b0 = *(const float4*)(&b_s[k][(colg << 3) + 0]);
      float4 b1 = *(const float4*)(&b_s[k][(colg << 3) + 4]);
      float av[8] = {a0.x, a0.y, a0.z, a0.w, a1.x, a1.y, a1.z, a1.w};
      float bv[8] = {b0.x, b0.y, b0.z, b0.w, b1.x, b1.y, b1.z, b1.w};
#pragma unroll
      for (int mi = 0; mi < 8; ++mi)
#pragma unroll
        for (int ni = 0; ni < 8; ++ni)
          acct[mi][ni] = fmaf(av[mi], bv[ni], acct[mi][ni]);
    }
#pragma unroll
    for (int mi = 0; mi < 8; ++mi)
#pragma unroll
      for (int ni = 0; ni < 8; ++ni) accm[mi][ni] += acct[mi][ni];
  }

  // epilogue: sigmoid + bias, store scores_for_choice
  float bb[8];
#pragma unroll
  for (int ni = 0; ni < 8; ++ni) bb[ni] = bias[(colg << 3) + ni];
#pragma unroll
  for (int mi = 0; mi < 8; ++mi) {
    const int r = m0 + (rowg << 3) + mi;
    float o[8];
#pragma unroll
    for (int ni = 0; ni < 8; ++ni)
      o[ni] = 1.0f / (1.0f + expf(-accm[mi][ni])) + bb[ni];
    *(float4*)(scores + (size_t)r * NEXP + (colg << 3) + 0) =
        make_float4(o[0], o[1], o[2], o[3]);
    *(float4*)(scores + (size_t)r * NEXP + (colg << 3) + 4) =
        make_float4(o[4], o[5], o[6], o[7]);
  }
}

// ---------------------------------------------------------------------------
// Phase 2: hierarchical top-k routing. One thread per token, 64 tokens/block,
// rows staged in LDS with XOR column swizzle (bank-conflict-free row reads).
// Tie-breaking replicates jax.lax.top_k: descending value, ascending index.
// ---------------------------------------------------------------------------
__global__ __launch_bounds__(64, 1) void route_kernel(
    const float* __restrict__ scores,   // [NTOK][NEXP] scores_for_choice
    float* __restrict__ out_idx,        // [NTOK][8] indices stored as float
    float* __restrict__ out_w)          // [NTOK][8]
{
  __shared__ float s_rows[64][256];     // element e of row r stored at col e^(r&31)
  const int tid = threadIdx.x;
  const int t0  = blockIdx.x << 6;

#pragma unroll 16
  for (int i = 0; i < 256; ++i) {
    const int r = i >> 2;
    const int c = ((i & 3) << 6) + tid;
    s_rows[r][c ^ (r & 31)] = scores[(size_t)(t0 + r) * NEXP + c];
  }
  __syncthreads();

  const int sw = tid & 31;
  const float* row = &s_rows[tid][0];
#define RD(e) row[(e) ^ sw]

  // group scores: sum of top-2 within each group of 32
  float gs[8];
#pragma unroll
  for (int g = 0; g < 8; ++g) {
    float m1 = -3.0e38f, m2 = -3.0e38f;
#pragma unroll
    for (int e = 0; e < 32; ++e) {
      const float v = RD(g * 32 + e);
      if (v > m1) { m2 = m1; m1 = v; }
      else if (v > m2) { m2 = v; }
    }
    gs[g] = m1 + m2;   // largest + second (matches top_k(...,2)[0].sum order)
  }

  // top-4 groups (strict > scan => earliest index on ties, like lax.top_k)
  int selmask = 0;
#pragma unroll
  for (int k = 0; k < 4; ++k) {
    float best = -3.0e38f; int bg = 0;
#pragma unroll
    for (int g = 0; g < 8; ++g) {
      if (!((selmask >> g) & 1) && gs[g] > best) { best = gs[g]; bg = g; }
    }
    selmask |= (1 << bg);
  }

  // masked top-8 over all 256 experts (masked value = 0.0, like the reference)
  float tv[8]; int ti[8];
#pragma unroll
  for (int i = 0; i < 8; ++i) { tv[i] = -3.0e38f; ti[i] = 0; }

#pragma unroll 4
  for (int e = 0; e < 256; ++e) {
    const bool sel = (selmask >> (e >> 5)) & 1;
    const float v = sel ? RD(e) : 0.0f;
    if (v > tv[7]) {            // strict >: equal values keep earlier index
      tv[7] = v; ti[7] = e;
#pragma unroll
      for (int p = 7; p > 0; --p) {
        if (tv[p] > tv[p - 1]) {
          const float tf = tv[p]; tv[p] = tv[p - 1]; tv[p - 1] = tf;
          const int   tt = ti[p]; ti[p] = ti[p - 1]; ti[p - 1] = tt;
        }
      }
    }
  }

  // weights gather from UNMASKED scores_for_choice, normalize, scale 2.5
  float w[8], denom = 0.f;
#pragma unroll
  for (int i = 0; i < 8; ++i) { w[i] = RD(ti[i]); denom += w[i]; }
  denom += 1e-20f;

  const size_t t = (size_t)t0 + tid;
#pragma unroll
  for (int i = 0; i < 8; ++i) {
    out_idx[t * 8 + i] = (float)ti[i];
    out_w[t * 8 + i]   = (w[i] / denom) * 2.5f;
  }
#undef RD
}

// ---------------------------------------------------------------------------
extern "C" void kernel_launch(void* const* d_in, const int* in_sizes, int n_in,
                              void* d_out, int out_size, void* d_ws, size_t ws_size,
                              hipStream_t stream)
{
  const float* hs   = (const float*)d_in[0];   // [4,4096,7168] fp32
  const float* w    = (const float*)d_in[1];   // [7168,256]    fp32
  const float* bias = (const float*)d_in[2];   // [256]         fp32
  float* out   = (float*)d_out;                // [16384*8 idx][16384*8 w] fp32
  float* score = (float*)d_ws;                 // scratch: 16384*256*4 = 16 MiB

  gemm_scores<<<NTOK / TM, 256, 0, stream>>>(hs, w, bias, score);
  route_kernel<<<NTOK / 64, 64, 0, stream>>>(score, out, out + (size_t)NTOK * 8);
}